// Round 14
// baseline (453.271 us; speedup 1.0000x reference)
//
#include <hip/hip_runtime.h>
#include <hip/hip_bf16.h>

// B=1, H=16, S=2048, KV=4096, D=64
// out[q][d] = (KEEP/sum_k p_k) * sum_k (drop_k * p_k * V[k][d])
// STATIC-MAX softmax: p = exp(s-8), s = qk/8 + {0,1} additive mask.
// R14: mask streamed at 16B/lane (uintx4 NT loads, one per row per 4-chunk
// quad), ballots kept in component-major layout (balv[i] bit l = elem 4l+i)
// and consumed directly via affine shift -- no interleave, no LDS, no prepass.

#define H_   16
#define S_   2048
#define KV_  4096
#define D_   64
#define NSPLIT 2
#define CPB  32                // chunks per block task (8 quads)

using bf16x8 = __attribute__((ext_vector_type(8))) __bf16;
using bf16x4 = __attribute__((ext_vector_type(4))) __bf16;
using f32x4  = __attribute__((ext_vector_type(4))) float;
using uintx4 = __attribute__((ext_vector_type(4))) unsigned;

constexpr float KEEP_SCALE = (float)(1.0 / (1.0 - 0.31881923790897965));
#define C_SC  0.18033688011112043f     // 0.125*log2(e)
#define C_ONE -10.098865286222744f     // (1-8)*log2(e)
#define C_ZRO -11.541560327111707f     // (0-8)*log2(e)

// ---- workspace layout (~33MB of ~2GB) ----
#define WS_FLAG 0
#define WS_K    256                        //  8 MB swizzled K tiles
#define WS_V    (WS_K + 8388608)           //  8 MB swizzled V^T tiles
#define WS_PART (WS_V + 8388608)           // 16 MB [2][H*S][64] f32
#define WS_LS   (WS_PART + 16777216)       // 256 KB [2][H*S] f32

__device__ __forceinline__ void gld16(const void* g, void* l) {
    __builtin_amdgcn_global_load_lds(
        (const __attribute__((address_space(1))) unsigned*)g,
        (__attribute__((address_space(3))) unsigned*)l, 16, 0, 0);
}

// ---------------------------------------------------------------------------
__global__ void detect_mask(const unsigned* __restrict__ m, int* __restrict__ flag) {
    __shared__ int bad;
    if (threadIdx.x == 0) bad = 0;
    __syncthreads();
    int ok = 1;
    for (int i = threadIdx.x; i < 4096; i += blockDim.x) {
        unsigned w = m[i];
        if (w > 1u && w != 0x3F800000u) ok = 0;
    }
    if (!ok) atomicOr(&bad, 1);
    __syncthreads();
    if (threadIdx.x == 0) *flag = bad;
}

// ---------------------------------------------------------------------------
// K -> bf16 tiles [h][chunk][8192B], pre-swizzled for linear gld_lds:
// LDS byte o holds K[row=o>>7][colbyte = (o&127) ^ ((row&7)<<4)].
// ---------------------------------------------------------------------------
__global__ __launch_bounds__(256)
void conv_k(const float* __restrict__ K, char* __restrict__ out) {
    const unsigned u = blockIdx.x * 256 + threadIdx.x;   // 16B unit (524288)
    const unsigned w = u & 511;
    const unsigned row = w >> 3;
    const unsigned dcol = (((w & 7) * 16) ^ ((row & 7) << 4)) >> 1;
    const unsigned tile = u >> 9, h = tile >> 6, c = tile & 63;
    const float* src = K + (((size_t)h * KV_) + c * 64 + row) * D_ + dcol;
    f32x4 f0 = *(const f32x4*)src;
    f32x4 f1 = *(const f32x4*)(src + 4);
    bf16x8 b;
    #pragma unroll
    for (int e = 0; e < 4; ++e) { b[e] = (__bf16)f0[e]; b[4 + e] = (__bf16)f1[e]; }
    *(bf16x8*)(out + (size_t)u * 16) = b;
}

// V^T tiles via per-block LDS transpose (row = d, cols = kv), same swizzle.
__global__ __launch_bounds__(256)
void conv_v(const float* __restrict__ V, char* __restrict__ out) {
    __shared__ __bf16 T[64][72];
    const int tile = blockIdx.x;                 // h*64 + c
    const int h = tile >> 6, c = tile & 63;
    const float* src = V + ((size_t)h * KV_ + c * 64) * D_;
    const int tid = threadIdx.x;
    #pragma unroll
    for (int r = 0; r < 4; ++r) {
        const int off = r * 1024 + tid * 4;
        const int kv = off >> 6, d = off & 63;
        f32x4 f = *(const f32x4*)(src + off);
        #pragma unroll
        for (int e = 0; e < 4; ++e) T[d + e][kv] = (__bf16)f[e];
    }
    __syncthreads();
    char* dst = out + (size_t)tile * 8192;
    #pragma unroll
    for (int r = 0; r < 2; ++r) {
        const int u = r * 256 + tid;
        const int d = u >> 3;
        const int kv0 = ((((u & 7) * 16) ^ ((d & 7) << 4))) >> 1;
        *(bf16x8*)(dst + (size_t)u * 16) = *(const bf16x8*)&T[d][kv0];
    }
}

// ---------------------------------------------------------------------------
// attn: 4 waves x 16q = 64 q/block (256 thr); chunk = 64 kv; NSPLIT=2 ->
// 1024 blocks. Mask: per 4-chunk quad, 16 uintx4 NT loads/wave (16B/lane);
// 64 ballots -> balv[4] in component-major order; application uses
// bit = balv[i] >> (16*g4 + 4t + g). K/V dbuf via gld_lds; P via swizzled LDS.
// ---------------------------------------------------------------------------
__global__ void attn_fwd(const float* __restrict__ Q,
              const unsigned char* __restrict__ Mb,
              const int* __restrict__ flagp,
              const char* __restrict__ Ktiles,
              const char* __restrict__ Vtiles,
              float* __restrict__ Part,
              float* __restrict__ Ls)
{
    __shared__ char smem[40960];          // 2 x (K 8KB | V 8KB) + 4 x 2KB P

    const int tid  = threadIdx.x;         // 0..255
    const int wave = tid >> 6, lane = tid & 63;
    const int lq   = lane & 15, g = lane >> 4;
    const int swz  = (lq & 7) << 4;

    // XCD swizzle (1024 % 8 == 0): 128 consecutive wg per XCD = 2 heads
    const int b  = blockIdx.x;
    const int wg = (b & 7) * 128 + (b >> 3);
    const int h  = wg >> 6;
    const int qt = (wg >> 1) & 31, split = wg & 1;
    const int q0w = qt * 64 + wave * 16;
    const int q_g = q0w + lq;

    const bool byteMode = (*flagp != 0);
    const unsigned* Mw = (const unsigned*)Mb;

    // Q fragments (B operand): lane holds Q[q_g][g*8 + 32*kk + e]
    bf16x8 bq[2];
    {
        const float* qrow = Q + ((size_t)h * S_ + q_g) * D_ + g * 8;
        #pragma unroll
        for (int kk = 0; kk < 2; ++kk) {
            f32x4 f0 = *(const f32x4*)(qrow + 32 * kk);
            f32x4 f1 = *(const f32x4*)(qrow + 32 * kk + 4);
            bf16x8 bb;
            #pragma unroll
            for (int e = 0; e < 4; ++e) { bb[e] = (__bf16)f0[e]; bb[4 + e] = (__bf16)f1[e]; }
            bq[kk] = bb;
        }
    }

    const char* gK = Ktiles + (size_t)h * 64 * 8192;
    const char* gV = Vtiles + (size_t)h * 64 * 8192;
    char* Pb = smem + 32768 + wave * 2048;

    float lsum = 0.f;
    f32x4 acc[4] = {};

    auto stage = [&](int buf, int c) {    // 256 thr x 16B x 4 = 16KB
        const char* sk = gK + (size_t)c * 8192 + tid * 16;
        const char* sv = gV + (size_t)c * 8192 + tid * 16;
        char* dk = smem + buf * 16384 + tid * 16;
        gld16(sk,        dk);
        gld16(sk + 4096, dk + 4096);
        gld16(sv,        dk + 8192);
        gld16(sv + 4096, dk + 12288);
    };

    // --- quad-wide mask stream: 16B/lane NT loads, component-major ballots
    uintx4  mr[16];                       // word mode: rows x 4 elems/lane
    unsigned mrb[16];                     // byte mode: rows x 4 bytes/lane
    auto load_quad = [&](int c0) {        // c0 = first chunk of the quad
        if (byteMode) {
            const unsigned char* bp = Mb + ((size_t)h * S_ + q0w) * KV_ + (size_t)c0 * 64 + 4 * lane;
            #pragma unroll
            for (int r = 0; r < 16; ++r)
                mrb[r] = __builtin_nontemporal_load((const unsigned*)(bp + (size_t)r * KV_));
        } else {
            const unsigned* wp = Mw + ((size_t)h * S_ + q0w) * KV_ + (size_t)c0 * 64 + 4 * lane;
            #pragma unroll
            for (int r = 0; r < 16; ++r)
                mr[r] = __builtin_nontemporal_load((const uintx4*)(wp + (size_t)r * KV_));
        }
    };
    unsigned long long balv[4];           // balv[j] bit l = elem (4l+j) of quad row lq
    auto ballot_quad = [&]() {
        #pragma unroll
        for (int r = 0; r < 16; ++r) {
            #pragma unroll
            for (int j = 0; j < 4; ++j) {
                const bool pred = byteMode ? (((mrb[r] >> (8 * j)) & 0xFFu) != 0u)
                                           : (mr[r][j] != 0u);
                unsigned long long bal = __ballot(pred);
                if (lq == r) balv[j] = bal;
            }
        }
    };

    const int cs = split * CPB, ce = cs + CPB;
    load_quad(cs);
    stage(0, cs);
    ballot_quad();
    __syncthreads();
    int cur = 0;

    for (int qd = 0; qd < CPB / 4; ++qd) {
        const bool moreq = (qd + 1 < CPB / 4);
        if (moreq) load_quad(cs + 4 * (qd + 1));   // 16B/lane NT stream

        #pragma unroll
        for (int g4 = 0; g4 < 4; ++g4) {
            const int c = cs + 4 * qd + g4;
            if (c + 1 < ce) stage(cur ^ 1, c + 1);
            const char* Kb = smem + cur * 16384;
            const char* Vb = Kb + 8192;

            // ---- QK^T (swapped): lane holds s for q=q_g, kv = 16t + 4g + i
            f32x4 st[4] = {};
            __builtin_amdgcn_s_setprio(1);
            #pragma unroll
            for (int t = 0; t < 4; ++t) {
                #pragma unroll
                for (int kk = 0; kk < 2; ++kk) {
                    bf16x8 ak = *(const bf16x8*)(Kb + (16 * t + lq) * 128 + ((16 * g + 64 * kk) ^ swz));
                    st[t] = __builtin_amdgcn_mfma_f32_16x16x32_bf16(ak, bq[kk], st[t], 0, 0, 0);
                }
            }
            __builtin_amdgcn_s_setprio(0);

            // ---- p = exp2(fma(s)); lsum; dropout via balv; P -> LDS
            const int shb = 16 * g4 + g;
            #pragma unroll
            for (int t = 0; t < 4; ++t) {
                bf16x4 pb;
                #pragma unroll
                for (int i = 0; i < 4; ++i) {
                    const int kvl = 16 * t + 4 * g + i;
                    const int kvg = c * 64 + kvl;
                    const bool one = (kvg < S_) ? (kvg > q_g) : (kvg - S_ <= q_g);
                    float v = fmaf(st[t][i], C_SC, one ? C_ONE : C_ZRO);
                    float pp = exp2f(v);
                    lsum += pp;
                    pb[i] = (__bf16)(((balv[i] >> (shb + 4 * t)) & 1) ? pp : 0.f);
                }
                *(bf16x4*)(Pb + lq * 128 + ((32 * t + 8 * g) ^ swz)) = pb;
            }

            asm volatile("s_waitcnt lgkmcnt(0)" ::: "memory");
            __builtin_amdgcn_sched_barrier(0);

            // ---- PV: acc += P[16q x 64kv] @ V[64kv x 64d]
            __builtin_amdgcn_s_setprio(1);
            #pragma unroll
            for (int c2 = 0; c2 < 2; ++c2) {
                bf16x8 ap = *(const bf16x8*)(Pb + lq * 128 + ((64 * c2 + 16 * g) ^ swz));
                #pragma unroll
                for (int nt = 0; nt < 4; ++nt) {
                    bf16x8 bv = *(const bf16x8*)(Vb + (16 * nt + lq) * 128 + ((64 * c2 + 16 * g) ^ swz));
                    acc[nt] = __builtin_amdgcn_mfma_f32_16x16x32_bf16(ap, bv, acc[nt], 0, 0, 0);
                }
            }
            __builtin_amdgcn_s_setprio(0);

            __syncthreads();     // readers done + next stage drained
            cur ^= 1;
        }

        if (moreq) ballot_quad();    // next quad's words (loads drained by now)
    }

    // ---- epilogue
    lsum += __shfl_xor(lsum, 16);
    lsum += __shfl_xor(lsum, 32);
    if (g == 0) Ls[((size_t)split * H_ + h) * S_ + q_g] = lsum;

    float* pa = Part + (((size_t)split * H_ + h) * S_ + q0w + 4 * g) * D_;
    #pragma unroll
    for (int i = 0; i < 4; ++i)
        #pragma unroll
        for (int nt = 0; nt < 4; ++nt)
            pa[i * D_ + nt * 16 + lq] = acc[nt][i];
}

// out = KEEP * (part0 + part1) / (l0 + l1)
__global__ __launch_bounds__(256)
void combine(const float* __restrict__ Part, const float* __restrict__ Ls,
             float* __restrict__ Out) {
    const int idx = blockIdx.x * 256 + threadIdx.x;   // H*S*16
    const int r  = idx >> 4;
    const int dg = (idx & 15) * 4;
    const f32x4 a = *(const f32x4*)(Part + (size_t)r * D_ + dg);
    const f32x4 b = *(const f32x4*)(Part + (size_t)(H_ * S_ + r) * D_ + dg);
    const float l = Ls[r] + Ls[H_ * S_ + r];
    const float s = KEEP_SCALE / l;
    f32x4 o;
    #pragma unroll
    for (int e = 0; e < 4; ++e) o[e] = (a[e] + b[e]) * s;
    *(f32x4*)(Out + (size_t)r * D_ + dg) = o;
}

extern "C" void kernel_launch(void* const* d_in, const int* in_sizes, int n_in,
                              void* d_out, int out_size, void* d_ws, size_t ws_size,
                              hipStream_t stream) {
    const float* Q = (const float*)d_in[0];
    const float* K = (const float*)d_in[1];
    const float* V = (const float*)d_in[2];
    const unsigned char* M = (const unsigned char*)d_in[3];
    char* ws = (char*)d_ws;
    int* flag = (int*)(ws + WS_FLAG);
    char* kt = ws + WS_K;
    char* vt = ws + WS_V;
    float* part = (float*)(ws + WS_PART);
    float* ls = (float*)(ws + WS_LS);

    detect_mask<<<1, 256, 0, stream>>>((const unsigned*)M, flag);
    conv_k<<<2048, 256, 0, stream>>>(K, kt);
    conv_v<<<1024, 256, 0, stream>>>(V, vt);
    attn_fwd<<<1024, 256, 0, stream>>>(Q, M, flag, kt, vt, part, ls);
    combine<<<2048, 256, 0, stream>>>(part, ls, (float*)d_out);
}

// Round 15
// 269.037 us; speedup vs baseline: 1.6848x; 1.6848x over previous
//
#include <hip/hip_runtime.h>
#include <hip/hip_bf16.h>

// B=1, H=16, S=2048, KV=4096, D=64
// out[q][d] = (KEEP/sum_k p_k) * sum_k (drop_k * p_k * V[k][d])
// STATIC-MAX softmax: p = exp(s-8), s = qk/8 + {0,1} additive mask.
// R15 = R13 (best verified, 8 waves x 16q, 16x16x32 MFMA, ballot mask fusion)
// with the mask stream widened to 8B/lane (uint2 NT, one load per row per
// chunk-PAIR) at +16 VGPR: bit(kvl, cp) = bal[i&1] >> (cp*32 + 8t + 2g + (i>>1)).

#define H_   16
#define S_   2048
#define KV_  4096
#define D_   64
#define NSPLIT 2
#define CPB  32                // chunks per block task (16 pairs)

using bf16x8 = __attribute__((ext_vector_type(8))) __bf16;
using bf16x4 = __attribute__((ext_vector_type(4))) __bf16;
using f32x4  = __attribute__((ext_vector_type(4))) float;
using uintx2 = __attribute__((ext_vector_type(2))) unsigned;

constexpr float KEEP_SCALE = (float)(1.0 / (1.0 - 0.31881923790897965));
#define C_SC  0.18033688011112043f     // 0.125*log2(e)
#define C_ONE -10.098865286222744f     // (1-8)*log2(e)
#define C_ZRO -11.541560327111707f     // (0-8)*log2(e)

// ---- workspace layout (~33MB of ~2GB) ----
#define WS_FLAG 0
#define WS_K    256                        //  8 MB swizzled K tiles
#define WS_V    (WS_K + 8388608)           //  8 MB swizzled V^T tiles
#define WS_PART (WS_V + 8388608)           // 16 MB [2][H*S][64] f32
#define WS_LS   (WS_PART + 16777216)       // 256 KB [2][H*S] f32

__device__ __forceinline__ void gld16(const void* g, void* l) {
    __builtin_amdgcn_global_load_lds(
        (const __attribute__((address_space(1))) unsigned*)g,
        (__attribute__((address_space(3))) unsigned*)l, 16, 0, 0);
}

// ---------------------------------------------------------------------------
__global__ void detect_mask(const unsigned* __restrict__ m, int* __restrict__ flag) {
    __shared__ int bad;
    if (threadIdx.x == 0) bad = 0;
    __syncthreads();
    int ok = 1;
    for (int i = threadIdx.x; i < 4096; i += blockDim.x) {
        unsigned w = m[i];
        if (w > 1u && w != 0x3F800000u) ok = 0;
    }
    if (!ok) atomicOr(&bad, 1);
    __syncthreads();
    if (threadIdx.x == 0) *flag = bad;
}

// ---------------------------------------------------------------------------
// K -> bf16 tiles [h][chunk][8192B], pre-swizzled for linear gld_lds:
// LDS byte o holds K[row=o>>7][colbyte = (o&127) ^ ((row&7)<<4)].
// ---------------------------------------------------------------------------
__global__ __launch_bounds__(256)
void conv_k(const float* __restrict__ K, char* __restrict__ out) {
    const unsigned u = blockIdx.x * 256 + threadIdx.x;   // 16B unit (524288)
    const unsigned w = u & 511;
    const unsigned row = w >> 3;
    const unsigned dcol = (((w & 7) * 16) ^ ((row & 7) << 4)) >> 1;
    const unsigned tile = u >> 9, h = tile >> 6, c = tile & 63;
    const float* src = K + (((size_t)h * KV_) + c * 64 + row) * D_ + dcol;
    f32x4 f0 = *(const f32x4*)src;
    f32x4 f1 = *(const f32x4*)(src + 4);
    bf16x8 b;
    #pragma unroll
    for (int e = 0; e < 4; ++e) { b[e] = (__bf16)f0[e]; b[4 + e] = (__bf16)f1[e]; }
    *(bf16x8*)(out + (size_t)u * 16) = b;
}

// V^T tiles via per-block LDS transpose (row = d, cols = kv), same swizzle.
__global__ __launch_bounds__(256)
void conv_v(const float* __restrict__ V, char* __restrict__ out) {
    __shared__ __bf16 T[64][72];
    const int tile = blockIdx.x;                 // h*64 + c
    const int h = tile >> 6, c = tile & 63;
    const float* src = V + ((size_t)h * KV_ + c * 64) * D_;
    const int tid = threadIdx.x;
    #pragma unroll
    for (int r = 0; r < 4; ++r) {
        const int off = r * 1024 + tid * 4;
        const int kv = off >> 6, d = off & 63;
        f32x4 f = *(const f32x4*)(src + off);
        #pragma unroll
        for (int e = 0; e < 4; ++e) T[d + e][kv] = (__bf16)f[e];
    }
    __syncthreads();
    char* dst = out + (size_t)tile * 8192;
    #pragma unroll
    for (int r = 0; r < 2; ++r) {
        const int u = r * 256 + tid;
        const int d = u >> 3;
        const int kv0 = ((((u & 7) * 16) ^ ((d & 7) << 4))) >> 1;
        *(bf16x8*)(dst + (size_t)u * 16) = *(const bf16x8*)&T[d][kv0];
    }
}

// ---------------------------------------------------------------------------
// attn: 8 waves x 16q = 128 q/block (512 thr); chunk = 64 kv; NSPLIT=2.
// Double-buffered K/V via gld_lds; per-wave swizzled P tile; pair-wide
// ballot mask streaming at 8B/lane.
// ---------------------------------------------------------------------------
__global__ __launch_bounds__(512, 4)
void attn_fwd(const float* __restrict__ Q,
              const unsigned char* __restrict__ Mb,
              const int* __restrict__ flagp,
              const char* __restrict__ Ktiles,
              const char* __restrict__ Vtiles,
              float* __restrict__ Part,
              float* __restrict__ Ls)
{
    __shared__ char smem[49152];          // 2 x (K 8KB | V 8KB) + 8 x 2KB P

    const int tid  = threadIdx.x;         // 0..511
    const int wave = tid >> 6, lane = tid & 63;
    const int lq   = lane & 15, g = lane >> 4;
    const int swz  = (lq & 7) << 4;

    // XCD swizzle (512 % 8 == 0): 64 consecutive wg per XCD = 2 heads
    const int b  = blockIdx.x;
    const int wg = (b & 7) * 64 + (b >> 3);
    const int h  = wg >> 5;
    const int qt = (wg >> 1) & 15, split = wg & 1;
    const int q0w = qt * 128 + wave * 16;
    const int q_g = q0w + lq;

    const bool byteMode = (*flagp != 0);
    const unsigned* Mw = (const unsigned*)Mb;

    // Q fragments (B operand): lane holds Q[q_g][g*8 + 32*kk + e]
    bf16x8 bq[2];
    {
        const float* qrow = Q + ((size_t)h * S_ + q_g) * D_ + g * 8;
        #pragma unroll
        for (int kk = 0; kk < 2; ++kk) {
            f32x4 f0 = *(const f32x4*)(qrow + 32 * kk);
            f32x4 f1 = *(const f32x4*)(qrow + 32 * kk + 4);
            bf16x8 bb;
            #pragma unroll
            for (int e = 0; e < 4; ++e) { bb[e] = (__bf16)f0[e]; bb[4 + e] = (__bf16)f1[e]; }
            bq[kk] = bb;
        }
    }

    const char* gK = Ktiles + (size_t)h * 64 * 8192;
    const char* gV = Vtiles + (size_t)h * 64 * 8192;
    char* Pb = smem + 32768 + wave * 2048;

    float lsum = 0.f;
    f32x4 acc[4] = {};

    auto stage = [&](int buf, int c) {    // 512 thr x 16B = 8KB per gld pass
        const char* sk = gK + (size_t)c * 8192 + tid * 16;
        const char* sv = gV + (size_t)c * 8192 + tid * 16;
        char* dk = smem + buf * 16384 + tid * 16;
        gld16(sk, dk);
        gld16(sv, dk + 8192);
    };

    // --- pair-wide mask stream: 8B/lane (word) / 2B (byte), NT loads.
    // Covered elems of the pair: e = 2*lane + j, e in [0,128) -> chunk
    // parity cp = e>>6, kvl = e & 63. Inverse: lane = cp*32 + (kvl>>1),
    // component j = kvl & 1.
    uintx2 mr2[16];
    auto load_pair = [&](int c0) {
        if (byteMode) {
            const unsigned char* bp = Mb + ((size_t)h * S_ + q0w) * KV_ + (size_t)c0 * 64 + 2 * lane;
            #pragma unroll
            for (int r = 0; r < 16; ++r) {
                unsigned short v = __builtin_nontemporal_load(
                    (const unsigned short*)(bp + (size_t)r * KV_));
                mr2[r].x = v; mr2[r].y = 0;
            }
        } else {
            const unsigned* wp = Mw + ((size_t)h * S_ + q0w) * KV_ + (size_t)c0 * 64 + 2 * lane;
            #pragma unroll
            for (int r = 0; r < 16; ++r)
                mr2[r] = __builtin_nontemporal_load((const uintx2*)(wp + (size_t)r * KV_));
        }
    };
    unsigned long long balp[2];           // balp[j] bit l = elem (2l+j) of pair
    auto ballot_pair = [&]() {
        #pragma unroll
        for (int r = 0; r < 16; ++r) {
            bool p0, p1;
            if (byteMode) {
                p0 = (mr2[r].x & 0xFFu) != 0u;
                p1 = ((mr2[r].x >> 8) & 0xFFu) != 0u;
            } else {
                p0 = mr2[r].x != 0u;
                p1 = mr2[r].y != 0u;
            }
            unsigned long long b0 = __ballot(p0);
            unsigned long long b1 = __ballot(p1);
            if (lq == r) { balp[0] = b0; balp[1] = b1; }
        }
    };

    const int cs = split * CPB, ce = cs + CPB;
    load_pair(cs);
    stage(0, cs);
    ballot_pair();
    __syncthreads();
    int cur = 0;

    for (int pd = 0; pd < CPB / 2; ++pd) {
        const bool morep = (pd + 1 < CPB / 2);
        if (morep) load_pair(cs + 2 * (pd + 1));   // NT 8B/lane stream

        #pragma unroll
        for (int cp = 0; cp < 2; ++cp) {
            const int c = cs + 2 * pd + cp;
            if (c + 1 < ce) stage(cur ^ 1, c + 1);
            const char* Kb = smem + cur * 16384;
            const char* Vb = Kb + 8192;

            // ---- QK^T (swapped): lane holds s for q=q_g, kv = 16t + 4g + i
            f32x4 st[4] = {};
            __builtin_amdgcn_s_setprio(1);
            #pragma unroll
            for (int t = 0; t < 4; ++t) {
                #pragma unroll
                for (int kk = 0; kk < 2; ++kk) {
                    bf16x8 ak = *(const bf16x8*)(Kb + (16 * t + lq) * 128 + ((16 * g + 64 * kk) ^ swz));
                    st[t] = __builtin_amdgcn_mfma_f32_16x16x32_bf16(ak, bq[kk], st[t], 0, 0, 0);
                }
            }
            __builtin_amdgcn_s_setprio(0);

            // ---- p = exp2(fma(s)); lsum; dropout via balp; P -> LDS
            #pragma unroll
            for (int t = 0; t < 4; ++t) {
                bf16x4 pb;
                #pragma unroll
                for (int i = 0; i < 4; ++i) {
                    const int kvl = 16 * t + 4 * g + i;
                    const int kvg = c * 64 + kvl;
                    const bool one = (kvg < S_) ? (kvg > q_g) : (kvg - S_ <= q_g);
                    float v = fmaf(st[t][i], C_SC, one ? C_ONE : C_ZRO);
                    float pp = exp2f(v);
                    lsum += pp;
                    const int sh = cp * 32 + 8 * t + 2 * g + (i >> 1);
                    pb[i] = (__bf16)(((balp[i & 1] >> sh) & 1) ? pp : 0.f);
                }
                *(bf16x4*)(Pb + lq * 128 + ((32 * t + 8 * g) ^ swz)) = pb;
            }

            asm volatile("s_waitcnt lgkmcnt(0)" ::: "memory");
            __builtin_amdgcn_sched_barrier(0);

            // ---- PV: acc += P[16q x 64kv] @ V[64kv x 64d]
            __builtin_amdgcn_s_setprio(1);
            #pragma unroll
            for (int c2 = 0; c2 < 2; ++c2) {
                bf16x8 ap = *(const bf16x8*)(Pb + lq * 128 + ((64 * c2 + 16 * g) ^ swz));
                #pragma unroll
                for (int nt = 0; nt < 4; ++nt) {
                    bf16x8 bv = *(const bf16x8*)(Vb + (16 * nt + lq) * 128 + ((64 * c2 + 16 * g) ^ swz));
                    acc[nt] = __builtin_amdgcn_mfma_f32_16x16x32_bf16(ap, bv, acc[nt], 0, 0, 0);
                }
            }
            __builtin_amdgcn_s_setprio(0);

            __syncthreads();     // readers done + next stage drained
            cur ^= 1;
        }

        if (morep) ballot_pair();    // next pair (loads drained by now)
    }

    // ---- epilogue
    lsum += __shfl_xor(lsum, 16);
    lsum += __shfl_xor(lsum, 32);
    if (g == 0) Ls[((size_t)split * H_ + h) * S_ + q_g] = lsum;

    float* pa = Part + (((size_t)split * H_ + h) * S_ + q0w + 4 * g) * D_;
    #pragma unroll
    for (int i = 0; i < 4; ++i)
        #pragma unroll
        for (int nt = 0; nt < 4; ++nt)
            pa[i * D_ + nt * 16 + lq] = acc[nt][i];
}

// out = KEEP * (part0 + part1) / (l0 + l1)
__global__ __launch_bounds__(256)
void combine(const float* __restrict__ Part, const float* __restrict__ Ls,
             float* __restrict__ Out) {
    const int idx = blockIdx.x * 256 + threadIdx.x;   // H*S*16
    const int r  = idx >> 4;
    const int dg = (idx & 15) * 4;
    const f32x4 a = *(const f32x4*)(Part + (size_t)r * D_ + dg);
    const f32x4 b = *(const f32x4*)(Part + (size_t)(H_ * S_ + r) * D_ + dg);
    const float l = Ls[r] + Ls[H_ * S_ + r];
    const float s = KEEP_SCALE / l;
    f32x4 o;
    #pragma unroll
    for (int e = 0; e < 4; ++e) o[e] = (a[e] + b[e]) * s;
    *(f32x4*)(Out + (size_t)r * D_ + dg) = o;
}

extern "C" void kernel_launch(void* const* d_in, const int* in_sizes, int n_in,
                              void* d_out, int out_size, void* d_ws, size_t ws_size,
                              hipStream_t stream) {
    const float* Q = (const float*)d_in[0];
    const float* K = (const float*)d_in[1];
    const float* V = (const float*)d_in[2];
    const unsigned char* M = (const unsigned char*)d_in[3];
    char* ws = (char*)d_ws;
    int* flag = (int*)(ws + WS_FLAG);
    char* kt = ws + WS_K;
    char* vt = ws + WS_V;
    float* part = (float*)(ws + WS_PART);
    float* ls = (float*)(ws + WS_LS);

    detect_mask<<<1, 256, 0, stream>>>((const unsigned*)M, flag);
    conv_k<<<2048, 256, 0, stream>>>(K, kt);
    conv_v<<<1024, 256, 0, stream>>>(V, vt);
    attn_fwd<<<512, 512, 0, stream>>>(Q, M, flag, kt, vt, part, ls);
    combine<<<2048, 256, 0, stream>>>(part, ls, (float*)d_out);
}

// Round 16
// 174.098 us; speedup vs baseline: 2.6035x; 1.5453x over previous
//
#include <hip/hip_runtime.h>
#include <hip/hip_bf16.h>

// B=1, H=16, S=2048, KV=4096, D=64
// out[q][d] = (KEEP/sum_k p_k) * sum_k (drop_k * p_k * V[k][d])
// STATIC-MAX softmax: p = exp(s-8), s = qk/8 + {0,1} additive mask.
// R16 = R13 + T3/T4: 3-deep LDS staging, raw s_barrier with COUNTED vmcnt
// (never drains to 0 in the main loop). Stage(c+2) issued at body top;
// vmcnt(18) before the per-body barrier ensures own stage(c+1) done while
// stage(c+2)+mask(c+2) stay in flight; ballot waits vmcnt(2) for mask(c+1).

#define H_   16
#define S_   2048
#define KV_  4096
#define D_   64
#define NSPLIT 2
#define CPB  32                // chunks per block task

using bf16x8 = __attribute__((ext_vector_type(8))) __bf16;
using bf16x4 = __attribute__((ext_vector_type(4))) __bf16;
using f32x4  = __attribute__((ext_vector_type(4))) float;

constexpr float KEEP_SCALE = (float)(1.0 / (1.0 - 0.31881923790897965));
#define C_SC  0.18033688011112043f     // 0.125*log2(e)
#define C_ONE -10.098865286222744f     // (1-8)*log2(e)
#define C_ZRO -11.541560327111707f     // (0-8)*log2(e)

// ---- workspace layout (~33MB of ~2GB) ----
#define WS_FLAG 0
#define WS_K    256                        //  8 MB swizzled K tiles
#define WS_V    (WS_K + 8388608)           //  8 MB swizzled V^T tiles
#define WS_PART (WS_V + 8388608)           // 16 MB [2][H*S][64] f32
#define WS_LS   (WS_PART + 16777216)       // 256 KB [2][H*S] f32

__device__ __forceinline__ void gld16(const void* g, void* l) {
    __builtin_amdgcn_global_load_lds(
        (const __attribute__((address_space(1))) unsigned*)g,
        (__attribute__((address_space(3))) unsigned*)l, 16, 0, 0);
}

// ---------------------------------------------------------------------------
__global__ void detect_mask(const unsigned* __restrict__ m, int* __restrict__ flag) {
    __shared__ int bad;
    if (threadIdx.x == 0) bad = 0;
    __syncthreads();
    int ok = 1;
    for (int i = threadIdx.x; i < 4096; i += blockDim.x) {
        unsigned w = m[i];
        if (w > 1u && w != 0x3F800000u) ok = 0;
    }
    if (!ok) atomicOr(&bad, 1);
    __syncthreads();
    if (threadIdx.x == 0) *flag = bad;
}

// ---------------------------------------------------------------------------
// K -> bf16 tiles [h][chunk][8192B], pre-swizzled for linear gld_lds:
// LDS byte o holds K[row=o>>7][colbyte = (o&127) ^ ((row&7)<<4)].
// ---------------------------------------------------------------------------
__global__ __launch_bounds__(256)
void conv_k(const float* __restrict__ K, char* __restrict__ out) {
    const unsigned u = blockIdx.x * 256 + threadIdx.x;   // 16B unit (524288)
    const unsigned w = u & 511;
    const unsigned row = w >> 3;
    const unsigned dcol = (((w & 7) * 16) ^ ((row & 7) << 4)) >> 1;
    const unsigned tile = u >> 9, h = tile >> 6, c = tile & 63;
    const float* src = K + (((size_t)h * KV_) + c * 64 + row) * D_ + dcol;
    f32x4 f0 = *(const f32x4*)src;
    f32x4 f1 = *(const f32x4*)(src + 4);
    bf16x8 b;
    #pragma unroll
    for (int e = 0; e < 4; ++e) { b[e] = (__bf16)f0[e]; b[4 + e] = (__bf16)f1[e]; }
    *(bf16x8*)(out + (size_t)u * 16) = b;
}

// V^T tiles via per-block LDS transpose (row = d, cols = kv), same swizzle.
__global__ __launch_bounds__(256)
void conv_v(const float* __restrict__ V, char* __restrict__ out) {
    __shared__ __bf16 T[64][72];
    const int tile = blockIdx.x;                 // h*64 + c
    const int h = tile >> 6, c = tile & 63;
    const float* src = V + ((size_t)h * KV_ + c * 64) * D_;
    const int tid = threadIdx.x;
    #pragma unroll
    for (int r = 0; r < 4; ++r) {
        const int off = r * 1024 + tid * 4;
        const int kv = off >> 6, d = off & 63;
        f32x4 f = *(const f32x4*)(src + off);
        #pragma unroll
        for (int e = 0; e < 4; ++e) T[d + e][kv] = (__bf16)f[e];
    }
    __syncthreads();
    char* dst = out + (size_t)tile * 8192;
    #pragma unroll
    for (int r = 0; r < 2; ++r) {
        const int u = r * 256 + tid;
        const int d = u >> 3;
        const int kv0 = ((((u & 7) * 16) ^ ((d & 7) << 4))) >> 1;
        *(bf16x8*)(dst + (size_t)u * 16) = *(const bf16x8*)&T[d][kv0];
    }
}

// ---------------------------------------------------------------------------
// attn: 8 waves x 16q = 128 q/block (512 thr); chunk = 64 kv; NSPLIT=2.
// 3-deep K/V staging via gld_lds + counted vmcnt + raw s_barrier.
// ---------------------------------------------------------------------------
__global__ __launch_bounds__(512, 4)
void attn_fwd(const float* __restrict__ Q,
              const unsigned char* __restrict__ Mb,
              const int* __restrict__ flagp,
              const char* __restrict__ Ktiles,
              const char* __restrict__ Vtiles,
              float* __restrict__ Part,
              float* __restrict__ Ls)
{
    __shared__ char smem[65536];          // 3 x (K 8KB | V 8KB) + 8 x 2KB P

    const int tid  = threadIdx.x;         // 0..511
    const int wave = tid >> 6, lane = tid & 63;
    const int lq   = lane & 15, g = lane >> 4;
    const int swz  = (lq & 7) << 4;

    // XCD swizzle (512 % 8 == 0): 64 consecutive wg per XCD = 2 heads
    const int b  = blockIdx.x;
    const int wg = (b & 7) * 64 + (b >> 3);
    const int h  = wg >> 5;
    const int qt = (wg >> 1) & 15, split = wg & 1;
    const int q0w = qt * 128 + wave * 16;
    const int q_g = q0w + lq;

    const bool byteMode = (*flagp != 0);
    const unsigned* Mw = (const unsigned*)Mb;

    // Q fragments (B operand): lane holds Q[q_g][g*8 + 32*kk + e]
    bf16x8 bq[2];
    {
        const float* qrow = Q + ((size_t)h * S_ + q_g) * D_ + g * 8;
        #pragma unroll
        for (int kk = 0; kk < 2; ++kk) {
            f32x4 f0 = *(const f32x4*)(qrow + 32 * kk);
            f32x4 f1 = *(const f32x4*)(qrow + 32 * kk + 4);
            bf16x8 bb;
            #pragma unroll
            for (int e = 0; e < 4; ++e) { bb[e] = (__bf16)f0[e]; bb[4 + e] = (__bf16)f1[e]; }
            bq[kk] = bb;
        }
    }

    const char* gK = Ktiles + (size_t)h * 64 * 8192;
    const char* gV = Vtiles + (size_t)h * 64 * 8192;
    char* Pb = smem + 49152 + wave * 2048;

    float lsum = 0.f;
    f32x4 acc[4] = {};

    auto stage = [&](int c) {             // into buf (c % 3); 2 vmem ops/thread
        const int buf = c % 3;
        const char* sk = gK + (size_t)c * 8192 + tid * 16;
        const char* sv = gV + (size_t)c * 8192 + tid * 16;
        char* dk = smem + buf * 16384 + tid * 16;
        gld16(sk, dk);
        gld16(sv, dk + 8192);
    };

    // --- fused mask streaming (r13): 16 coalesced 4B loads -> 16 ballots
    unsigned mreg[16];
    auto load_bits = [&](int cc) {        // 16 vmem ops/thread
        if (byteMode) {
            const unsigned char* base = Mb + ((size_t)h * S_ + q0w) * KV_ + (size_t)cc * 64 + lane;
            #pragma unroll
            for (int i = 0; i < 16; ++i) mreg[i] = base[(size_t)i * KV_];
        } else {
            const unsigned* base = Mw + ((size_t)h * S_ + q0w) * KV_ + (size_t)cc * 64 + lane;
            #pragma unroll
            for (int i = 0; i < 16; ++i) mreg[i] = base[(size_t)i * KV_];
        }
    };
    unsigned long long balv;
    auto ballot_bits = [&]() {
        unsigned long long sav = 0;
        #pragma unroll
        for (int i = 0; i < 16; ++i) {
            unsigned long long bal = __ballot(mreg[i] != 0u);
            if (lq == i) sav = bal;       // all 4 g-lanes of row i keep its word
        }
        balv = sav;
    };

    const int cs = split * CPB, ce = cs + CPB;

    // ---- prologue: queue = [mask(cs)16, stage(cs)2, stage(cs+1)2]
    load_bits(cs);
    stage(cs);
    stage(cs + 1);
    asm volatile("s_waitcnt vmcnt(4)" ::: "memory");       // mask(cs) done
    __builtin_amdgcn_sched_barrier(0);
    ballot_bits();                                          // balv for cs
    load_bits(cs + 1);                                      // queue: [st(cs)2, st(cs+1)2, mask(cs+1)16]
    asm volatile("s_waitcnt vmcnt(18)" ::: "memory");       // own stage(cs) done
    __builtin_amdgcn_sched_barrier(0);
    __builtin_amdgcn_s_barrier();                           // all waves' stage(cs) done

    for (int c = cs; c < ce; ++c) {
        const bool m1 = (c + 1 < ce), m2 = (c + 2 < ce);
        if (m2) stage(c + 2);             // overwrites buf[(c+2)%3]=(c-1)%3: readers done (last barrier)
        const char* Kb = smem + (c % 3) * 16384;
        const char* Vb = Kb + 8192;
        const unsigned long long mb = balv;

        // ---- QK^T (swapped): lane holds s for q=q_g, kv = 16t + 4g + i
        f32x4 st[4] = {};
        __builtin_amdgcn_s_setprio(1);
        #pragma unroll
        for (int t = 0; t < 4; ++t) {
            #pragma unroll
            for (int kk = 0; kk < 2; ++kk) {
                bf16x8 ak = *(const bf16x8*)(Kb + (16 * t + lq) * 128 + ((16 * g + 64 * kk) ^ swz));
                st[t] = __builtin_amdgcn_mfma_f32_16x16x32_bf16(ak, bq[kk], st[t], 0, 0, 0);
            }
        }
        __builtin_amdgcn_s_setprio(0);

        // ---- p = exp2(fma(s)); lsum; dropout; P -> per-wave swizzled LDS
        #pragma unroll
        for (int t = 0; t < 4; ++t) {
            bf16x4 pb;
            #pragma unroll
            for (int i = 0; i < 4; ++i) {
                const int kvl = 16 * t + 4 * g + i;
                const int kvg = c * 64 + kvl;
                const bool one = (kvg < S_) ? (kvg > q_g) : (kvg - S_ <= q_g);
                float v = fmaf(st[t][i], C_SC, one ? C_ONE : C_ZRO);
                float pp = exp2f(v);
                lsum += pp;
                pb[i] = (__bf16)(((mb >> kvl) & 1) ? pp : 0.f);
            }
            *(bf16x4*)(Pb + lq * 128 + ((32 * t + 8 * g) ^ swz)) = pb;
        }

        asm volatile("s_waitcnt lgkmcnt(0)" ::: "memory");
        __builtin_amdgcn_sched_barrier(0);

        // ---- PV: acc += P[16q x 64kv] @ V[64kv x 64d]
        __builtin_amdgcn_s_setprio(1);
        #pragma unroll
        for (int c2 = 0; c2 < 2; ++c2) {
            bf16x8 ap = *(const bf16x8*)(Pb + lq * 128 + ((64 * c2 + 16 * g) ^ swz));
            #pragma unroll
            for (int nt = 0; nt < 4; ++nt) {
                bf16x8 bv = *(const bf16x8*)(Vb + (16 * nt + lq) * 128 + ((64 * c2 + 16 * g) ^ swz));
                acc[nt] = __builtin_amdgcn_mfma_f32_16x16x32_bf16(ap, bv, acc[nt], 0, 0, 0);
            }
        }
        __builtin_amdgcn_s_setprio(0);

        // ---- ballot(c+1): queue = [mask(c+1)16, stage(c+2)2?]
        if (m1) {
            if (m2) { asm volatile("s_waitcnt vmcnt(2)" ::: "memory"); }
            else    { asm volatile("s_waitcnt vmcnt(0)" ::: "memory"); }
            __builtin_amdgcn_sched_barrier(0);
            ballot_bits();                 // balv for c+1
            if (m2) load_bits(c + 2);      // queue: [stage(c+2)2, mask(c+2)16]
        }

        // ---- end-of-body: own stage(c+1) done (allow stage(c+2)+mask(c+2))
        if (m1) {
            if (m2) { asm volatile("s_waitcnt vmcnt(18)" ::: "memory"); }
            else    { asm volatile("s_waitcnt vmcnt(0)" ::: "memory"); }
            __builtin_amdgcn_sched_barrier(0);
            __builtin_amdgcn_s_barrier();  // all waves: stage(c+1) visible,
                                           // buf[c%3] readers done
        }
    }

    // ---- epilogue
    lsum += __shfl_xor(lsum, 16);
    lsum += __shfl_xor(lsum, 32);
    if (g == 0) Ls[((size_t)split * H_ + h) * S_ + q_g] = lsum;

    float* pa = Part + (((size_t)split * H_ + h) * S_ + q0w + 4 * g) * D_;
    #pragma unroll
    for (int i = 0; i < 4; ++i)
        #pragma unroll
        for (int nt = 0; nt < 4; ++nt)
            pa[i * D_ + nt * 16 + lq] = acc[nt][i];
}

// out = KEEP * (part0 + part1) / (l0 + l1)
__global__ __launch_bounds__(256)
void combine(const float* __restrict__ Part, const float* __restrict__ Ls,
             float* __restrict__ Out) {
    const int idx = blockIdx.x * 256 + threadIdx.x;   // H*S*16
    const int r  = idx >> 4;
    const int dg = (idx & 15) * 4;
    const f32x4 a = *(const f32x4*)(Part + (size_t)r * D_ + dg);
    const f32x4 b = *(const f32x4*)(Part + (size_t)(H_ * S_ + r) * D_ + dg);
    const float l = Ls[r] + Ls[H_ * S_ + r];
    const float s = KEEP_SCALE / l;
    f32x4 o;
    #pragma unroll
    for (int e = 0; e < 4; ++e) o[e] = (a[e] + b[e]) * s;
    *(f32x4*)(Out + (size_t)r * D_ + dg) = o;
}

extern "C" void kernel_launch(void* const* d_in, const int* in_sizes, int n_in,
                              void* d_out, int out_size, void* d_ws, size_t ws_size,
                              hipStream_t stream) {
    const float* Q = (const float*)d_in[0];
    const float* K = (const float*)d_in[1];
    const float* V = (const float*)d_in[2];
    const unsigned char* M = (const unsigned char*)d_in[3];
    char* ws = (char*)d_ws;
    int* flag = (int*)(ws + WS_FLAG);
    char* kt = ws + WS_K;
    char* vt = ws + WS_V;
    float* part = (float*)(ws + WS_PART);
    float* ls = (float*)(ws + WS_LS);

    detect_mask<<<1, 256, 0, stream>>>((const unsigned*)M, flag);
    conv_k<<<2048, 256, 0, stream>>>(K, kt);
    conv_v<<<1024, 256, 0, stream>>>(V, vt);
    attn_fwd<<<512, 512, 0, stream>>>(Q, M, flag, kt, vt, part, ls);
    combine<<<2048, 256, 0, stream>>>(part, ls, (float*)d_out);
}